// Round 1
// baseline (133.752 us; speedup 1.0000x reference)
//
#include <hip/hip_runtime.h>
#include <hip/hip_bf16.h>

#define D 128
#define RBASE 40
#define NREL (2 * RBASE)
#define WSZ 2048   // edges scanned per block (window)

// ---------------------------------------------------------------------------
// Self transform: out[i][j] = sum_k x[i][k] * W_self[j][k] + b_self[j]
// Tile: 32 rows x 128 cols per block, 256 threads, 4x4 register tile.
// ---------------------------------------------------------------------------
__global__ void self_kernel(const float* __restrict__ x,
                            const float* __restrict__ Ws,
                            const float* __restrict__ bs,
                            float* __restrict__ out, int n) {
    __shared__ float vbuf[32][D];
    const int row0 = blockIdx.x * 32;
    const int tid  = threadIdx.x;

    // stage 32 x-rows into LDS (float4, coalesced)
    for (int li = tid; li < 32 * (D / 4); li += 256) {
        int r = li >> 5;          // 0..31
        int c = li & 31;          // float4 index within row
        int row = row0 + r;
        float4 v = make_float4(0.f, 0.f, 0.f, 0.f);
        if (row < n)
            v = reinterpret_cast<const float4*>(x + (size_t)row * D)[c];
        reinterpret_cast<float4*>(vbuf[r])[c] = v;
    }
    __syncthreads();

    const int eg = tid >> 5;   // 0..7  -> rows eg*4 .. eg*4+3
    const int jg = tid & 31;   // 0..31 -> cols jg*4 .. jg*4+3

    float acc[4][4];
    #pragma unroll
    for (int b = 0; b < 4; ++b)
        #pragma unroll
        for (int a = 0; a < 4; ++a) acc[b][a] = 0.f;

    #pragma unroll 4
    for (int k = 0; k < D; k += 4) {
        float4 w[4], v[4];
        #pragma unroll
        for (int a = 0; a < 4; ++a)
            w[a] = *reinterpret_cast<const float4*>(Ws + (size_t)(jg * 4 + a) * D + k);
        #pragma unroll
        for (int b = 0; b < 4; ++b)
            v[b] = *reinterpret_cast<const float4*>(&vbuf[eg * 4 + b][k]);
        #pragma unroll
        for (int b = 0; b < 4; ++b)
            #pragma unroll
            for (int a = 0; a < 4; ++a)
                acc[b][a] += v[b].x * w[a].x + v[b].y * w[a].y +
                             v[b].z * w[a].z + v[b].w * w[a].w;
    }

    const float4 bias = *reinterpret_cast<const float4*>(bs + jg * 4);
    #pragma unroll
    for (int b = 0; b < 4; ++b) {
        int row = row0 + eg * 4 + b;
        if (row < n) {
            float4 res = make_float4(acc[b][0] + bias.x, acc[b][1] + bias.y,
                                     acc[b][2] + bias.z, acc[b][3] + bias.w);
            *reinterpret_cast<float4*>(out + (size_t)row * D + jg * 4) = res;
        }
    }
}

// ---------------------------------------------------------------------------
// Edge messages, grouped by relation at runtime (no workspace needed).
// Virtual edge e in [0, 2n):
//   e <  n : out[dst[e]]   += W_rel[rel[e]]       @ x[src[e]]   + b_rel[rel[e]]
//   e >= n : out[src[e-n]] += W_rel[rel[e-n]+40]  @ x[dst[e-n]] + b_rel[rel[e-n]+40]
// Grid: (80 relations, ceil(2n/WSZ) windows). Each block scans its window,
// compacts edges matching its relation into LDS, then runs 32-edge tiles of
// a register-tiled GEMM (4x4 per thread) and atomicAdds the results.
// ---------------------------------------------------------------------------
__global__ void edge_kernel(const float* __restrict__ x,
                            const float* __restrict__ Wr,
                            const float* __restrict__ br,
                            const int* __restrict__ src,
                            const int* __restrict__ dst,
                            const int* __restrict__ rel,
                            float* __restrict__ out, int n) {
    __shared__ int   lds_cnt;
    __shared__ int   lds_list[WSZ];
    __shared__ float vbuf[32][D];
    __shared__ int   sE[32];
    __shared__ int   dE[32];

    const int r   = blockIdx.x;            // relation 0..79
    const int tid = threadIdx.x;
    const int wbase = blockIdx.y * WSZ;
    const int etot  = 2 * n;

    if (tid == 0) lds_cnt = 0;
    __syncthreads();

    // scan window, compact matching virtual-edge ids
    for (int i = tid; i < WSZ; i += 256) {
        int e = wbase + i;
        if (e < etot) {
            int er = (e < n) ? rel[e] : (rel[e - n] + RBASE);
            if (er == r) {
                int p = atomicAdd(&lds_cnt, 1);
                lds_list[p] = e;
            }
        }
    }
    __syncthreads();
    const int m = lds_cnt;
    if (m == 0) return;

    const float* W  = Wr + (size_t)r * D * D;
    const int    jg = tid & 31;   // col group
    const int    eg = tid >> 5;   // edge group
    const float4 bias = *reinterpret_cast<const float4*>(br + (size_t)r * D + jg * 4);

    for (int t0 = 0; t0 < m; t0 += 32) {
        // resolve src/dst nodes for up to 32 edges of this tile
        if (tid < 32) {
            int s = -1, d = -1;
            if (t0 + tid < m) {
                int e = lds_list[t0 + tid];
                if (e < n) { s = src[e];     d = dst[e];     }
                else       { s = dst[e - n]; d = src[e - n]; }
            }
            sE[tid] = s;
            dE[tid] = d;
        }
        __syncthreads();

        // gather x[src] rows into LDS
        for (int li = tid; li < 32 * (D / 4); li += 256) {
            int row = li >> 5;
            int c   = li & 31;
            int s   = sE[row];
            float4 v = make_float4(0.f, 0.f, 0.f, 0.f);
            if (s >= 0)
                v = reinterpret_cast<const float4*>(x + (size_t)s * D)[c];
            reinterpret_cast<float4*>(vbuf[row])[c] = v;
        }
        __syncthreads();

        float acc[4][4];
        #pragma unroll
        for (int b = 0; b < 4; ++b)
            #pragma unroll
            for (int a = 0; a < 4; ++a) acc[b][a] = 0.f;

        #pragma unroll 4
        for (int k = 0; k < D; k += 4) {
            float4 w[4], v[4];
            #pragma unroll
            for (int a = 0; a < 4; ++a)
                w[a] = *reinterpret_cast<const float4*>(W + (size_t)(jg * 4 + a) * D + k);
            #pragma unroll
            for (int b = 0; b < 4; ++b)
                v[b] = *reinterpret_cast<const float4*>(&vbuf[eg * 4 + b][k]);
            #pragma unroll
            for (int b = 0; b < 4; ++b)
                #pragma unroll
                for (int a = 0; a < 4; ++a)
                    acc[b][a] += v[b].x * w[a].x + v[b].y * w[a].y +
                                 v[b].z * w[a].z + v[b].w * w[a].w;
        }

        // bias + scatter-add
        #pragma unroll
        for (int b = 0; b < 4; ++b) {
            int row = eg * 4 + b;
            int dn  = dE[row];
            if (dn >= 0) {
                float* o = out + (size_t)dn * D + jg * 4;
                atomicAdd(o + 0, acc[b][0] + bias.x);
                atomicAdd(o + 1, acc[b][1] + bias.y);
                atomicAdd(o + 2, acc[b][2] + bias.z);
                atomicAdd(o + 3, acc[b][3] + bias.w);
            }
        }
        __syncthreads();   // protect sE/dE/vbuf before next tile
    }
}

extern "C" void kernel_launch(void* const* d_in, const int* in_sizes, int n_in,
                              void* d_out, int out_size, void* d_ws, size_t ws_size,
                              hipStream_t stream) {
    const float* x   = (const float*)d_in[0];
    const float* Ws  = (const float*)d_in[1];
    const float* bs  = (const float*)d_in[2];
    const float* Wr  = (const float*)d_in[3];
    const float* br  = (const float*)d_in[4];
    const int*   src = (const int*)d_in[5];
    const int*   dst = (const int*)d_in[6];
    const int*   rel = (const int*)d_in[7];
    float*       out = (float*)d_out;

    const int n = in_sizes[5];   // number of edges / nodes (N)
    if (n <= 0) return;

    // 1) self transform writes the full output (including self bias)
    self_kernel<<<dim3((n + 31) / 32), 256, 0, stream>>>(x, Ws, bs, out, n);

    // 2) relation-grouped edge messages, atomically accumulated on top
    const int nw = (2 * n + WSZ - 1) / WSZ;
    edge_kernel<<<dim3(NREL, nw), 256, 0, stream>>>(x, Wr, br, src, dst, rel, out, n);
}